// Round 7
// baseline (281.571 us; speedup 1.0000x reference)
//
#include <hip/hip_runtime.h>
#include <hip/hip_bf16.h>
#include <stdint.h>

// ---- problem constants ----
#define C_CLS  100000
#define DDIM   512
#define BROWS  512
#define NT     64          // classes per block
#define NSTEP  16          // K steps of 32
#define EPSN   1e-5f

typedef __attribute__((ext_vector_type(8))) short short8;
typedef __attribute__((ext_vector_type(4))) float f32x4;

// d_ws float layout:
//   [0    .. 4096)  : 256 gemm accumulation slots, stride 16 floats
//   [4096 .. 5120)  : 64 label accumulation slots, stride 16 floats
//   byte 32768 ...  : xnf — bf16 A in MFMA fragment layout (512 KB)

__device__ inline unsigned pk2(float a, float b) {
  __hip_bfloat162 h = __float22bfloat162_rn(make_float2(a, b));
  unsigned u; __builtin_memcpy(&u, &h, 4); return u;
}

// Normalize each input row -> bf16, fragment order:
// cell idx (16B) = (s*32 + r16)*64 + khalf*16 + row; s=k>>5, r16=b>>4,
// khalf=(k>>3)&3, row=b&15. Also zeroes the ws accumulation slots.
__global__ void __launch_bounds__(64) k_norm_input(const float* __restrict__ in,
                                                   uint4* __restrict__ xnf,
                                                   float* __restrict__ ws) {
  int b = blockIdx.x;
  int lane = threadIdx.x;              // lane covers k = lane*8 .. +7
  if (lane == 0) {                     // zero accumulation slots
    if (b < 256) ws[b * 16] = 0.f;
    else if (b < 320) ws[4096 + (b - 256) * 16] = 0.f;
  }
  const float4* row = (const float4*)(in + b * DDIM);
  float4 v0 = row[lane * 2];
  float4 v1 = row[lane * 2 + 1];
  float ss = v0.x*v0.x + v0.y*v0.y + v0.z*v0.z + v0.w*v0.w
           + v1.x*v1.x + v1.y*v1.y + v1.z*v1.z + v1.w*v1.w;
#pragma unroll
  for (int o = 32; o >= 1; o >>= 1) ss += __shfl_xor(ss, o, 64);
  float sc = 1.f / fmaxf(sqrtf(ss), EPSN);
  uint4 o4;
  o4.x = pk2(v0.x*sc, v0.y*sc);
  o4.y = pk2(v0.z*sc, v0.w*sc);
  o4.z = pk2(v1.x*sc, v1.y*sc);
  o4.w = pk2(v1.z*sc, v1.w*sc);
  int idx = ((lane >> 2) * 32 + (b >> 4)) * 64 + (lane & 3) * 16 + (b & 15);
  xnf[idx] = o4;
}

// Fused GEMM + loss. 512 threads (8 waves), wave owns 64 rows (m=4) x 64
// classes (n=4). NO LDS, NO barriers: W streams HBM->reg->bf16->MFMA B-frag
// directly (2-step prefetch); A-frags stream L2->reg (1-step double buffer).
// Per-class norm^2 accumulated in-register, finished with two shfl_xor.
__global__ void __launch_bounds__(512, 2)
k_gemm(const uint4* __restrict__ xnf, const float* __restrict__ wt,
       const float* __restrict__ bias, float* __restrict__ ws) {
  const int tid  = threadIdx.x;
  const int lane = tid & 63;
  const int wv   = tid >> 6;                 // 0..7, rows [wv*64, +64)
  const int cbase = blockIdx.x * NT;

  const int wrow_ = lane & 15;               // class-within-frag
  const int koff  = (lane >> 4) * 8;         // k-chunk within step

  // B-frag source pointers: lane l, frag n -> row (cbase + n*16 + (l&15)),
  // 8 consecutive f32 at k = s*32 + (l>>4)*8. Rows clamped; masked in epilogue.
  auto rowp = [&](int n) {
    int c = cbase + n * 16 + wrow_;
    if (c >= C_CLS) c = C_CLS - 1;
    return wt + (size_t)c * DDIM + koff;
  };
  const float* wp0 = rowp(0);
  const float* wp1 = rowp(1);
  const float* wp2 = rowp(2);
  const float* wp3 = rowp(3);

  // A frags: cell = (s*32 + wv*4 + m)*64 + lane
  const uint4* abase = xnf + (wv * 4) * 64 + lane;   // + s*2048 + m*64

  float4 wA[8], wB[8];     // [n*2 + half], f32 W in flight (2 steps deep)
  short8 aA[4], aB[4];     // A frags (double buffer)
  short8 wf[4];            // current step's converted B frags
  float wsq[4] = {0.f, 0.f, 0.f, 0.f};
  f32x4 acc[4][4];
#pragma unroll
  for (int m = 0; m < 4; m++)
#pragma unroll
    for (int n = 0; n < 4; n++) acc[m][n] = (f32x4)(0.f);

  auto loadW = [&](float4 (&w)[8], int s) {
    const int o = s * 32;
    w[0] = *(const float4*)(wp0 + o); w[1] = *(const float4*)(wp0 + o + 4);
    w[2] = *(const float4*)(wp1 + o); w[3] = *(const float4*)(wp1 + o + 4);
    w[4] = *(const float4*)(wp2 + o); w[5] = *(const float4*)(wp2 + o + 4);
    w[6] = *(const float4*)(wp3 + o); w[7] = *(const float4*)(wp3 + o + 4);
  };
  auto loadA = [&](short8 (&af)[4], int s) {
    const uint4* p = abase + s * 2048;
#pragma unroll
    for (int m = 0; m < 4; m++)
      af[m] = *(const short8*)(p + m * 64);
  };
  auto cvtW = [&](const float4 (&w)[8]) {
#pragma unroll
    for (int n = 0; n < 4; n++) {
      float4 a = w[n * 2], b = w[n * 2 + 1];
      wsq[n] += a.x*a.x + a.y*a.y + a.z*a.z + a.w*a.w
              + b.x*b.x + b.y*b.y + b.z*b.z + b.w*b.w;
      uint4 u;
      u.x = pk2(a.x, a.y); u.y = pk2(a.z, a.w);
      u.z = pk2(b.x, b.y); u.w = pk2(b.z, b.w);
      __builtin_memcpy(&wf[n], &u, 16);
    }
  };
  auto domfma = [&](const short8 (&af)[4]) {
#pragma unroll
    for (int n = 0; n < 4; n++)
#pragma unroll
      for (int m = 0; m < 4; m++)
        acc[m][n] = __builtin_amdgcn_mfma_f32_16x16x32_bf16(af[m], wf[n], acc[m][n], 0, 0, 0);
  };

  // prologue: W(0),W(1) and A(0) in flight
  loadW(wA, 0);
  loadW(wB, 1);
  loadA(aA, 0);

#pragma unroll 1
  for (int s2 = 0; s2 < 8; ++s2) {
    const int s0 = s2 * 2;
    // even step s0: consume wA/aA
    loadA(aB, s0 + 1);
    cvtW(wA);
    if (s2 < 7) loadW(wA, s0 + 2);
    domfma(aA);
    // odd step s0+1: consume wB/aB
    if (s2 < 7) loadA(aA, s0 + 2);
    cvtW(wB);
    if (s2 < 7) loadW(wB, s0 + 3);
    domfma(aB);
  }

  // ---- epilogue: finish norms in-register, loss over 64 elems/thread ----
  const float bv = bias[0];
  float lsum = 0.f;
#pragma unroll
  for (int n = 0; n < 4; n++) {
    float t = wsq[n];
    t += __shfl_xor(t, 16, 64);
    t += __shfl_xor(t, 32, 64);          // all 4 k-groups summed
    float s64 = 64.f / fmaxf(sqrtf(t), EPSN);   // fold S and 1/||w||
    bool valid = (cbase + n * 16 + wrow_) < C_CLS;
#pragma unroll
    for (int m = 0; m < 4; m++) {
#pragma unroll
      for (int i = 0; i < 4; i++) {
        // x = 64*cos - bias <= ~51: upper clamp provably inactive; lower
        // clip irrelevant (exp underflow). log1p(z) ~= z - z^2/2, z<=1/32.
        float x = fmaf(acc[m][n][i], s64, -bv);
        float z = __expf(x);
        float l = fmaf(-0.5f * z, z, z);
        if (z > 0.03125f) l = __logf(1.f + z);   // rare (~1e-4)
        lsum += valid ? l : 0.f;
      }
    }
  }
#pragma unroll
  for (int o = 32; o >= 1; o >>= 1) lsum += __shfl_xor(lsum, o, 64);
  if (lane == 0) atomicAdd(&ws[(blockIdx.x & 255) * 16], lsum);
}

// Label correction: replace n_loss(b, label_b) by p_loss(b, label_b), full f32.
__global__ void __launch_bounds__(64) k_label(const float* __restrict__ in,
                                              const float* __restrict__ wt,
                                              const int* __restrict__ label,
                                              const float* __restrict__ bias,
                                              float* __restrict__ ws) {
  int b = blockIdx.x;
  int lane = threadIdx.x;
  int c = label[b];
  const float4* xr = (const float4*)(in + b * DDIM);
  const float4* wr = (const float4*)(wt + (size_t)c * DDIM);
  float dt = 0.f, sx = 0.f, sw = 0.f;
#pragma unroll
  for (int i = 0; i < 2; i++) {
    float4 x = xr[lane * 2 + i];
    float4 w = wr[lane * 2 + i];
    dt += x.x*w.x + x.y*w.y + x.z*w.z + x.w*w.w;
    sx += x.x*x.x + x.y*x.y + x.z*x.z + x.w*x.w;
    sw += w.x*w.x + w.y*w.y + w.z*w.z + w.w*w.w;
  }
#pragma unroll
  for (int o = 32; o >= 1; o >>= 1) {
    dt += __shfl_xor(dt, o, 64);
    sx += __shfl_xor(sx, o, 64);
    sw += __shfl_xor(sw, o, 64);
  }
  if (lane == 0) {
    float bv = bias[0];
    float cosv = dt / (fmaxf(sqrtf(sx), EPSN) * fmaxf(sqrtf(sw), EPSN));
    float cp = 64.f * (cosv - 0.4f) - bv;
    cp = fminf(fmaxf(cp, -64.f), 64.f);
    float pl = log1pf(expf(-cp));
    float cn = 64.f * cosv - bv;
    cn = fminf(fmaxf(cn, -64.f), 64.f);
    float nl = log1pf(expf(cn));
    atomicAdd(&ws[4096 + (b & 63) * 16], pl - nl);
  }
}

// Merge the 256 gemm slots + 64 label slots, scale by 1/B.
__global__ void __launch_bounds__(64) k_final(const float* __restrict__ ws,
                                              float* __restrict__ out) {
  int lane = threadIdx.x;
  float s = ws[lane * 16] + ws[(lane + 64) * 16]
          + ws[(lane + 128) * 16] + ws[(lane + 192) * 16]
          + ws[4096 + lane * 16];
#pragma unroll
  for (int o = 32; o >= 1; o >>= 1) s += __shfl_xor(s, o, 64);
  if (lane == 0) out[0] = s * (1.f / 512.f);
}

extern "C" void kernel_launch(void* const* d_in, const int* in_sizes, int n_in,
                              void* d_out, int out_size, void* d_ws, size_t ws_size,
                              hipStream_t stream) {
  const float* input  = (const float*)d_in[0];
  const int*   label  = (const int*)d_in[1];
  const float* weight = (const float*)d_in[2];
  const float* bias   = (const float*)d_in[3];
  float* out = (float*)d_out;
  float* ws  = (float*)d_ws;
  uint4* xnf = (uint4*)((char*)d_ws + 32768);

  k_norm_input<<<BROWS, 64, 0, stream>>>(input, xnf, ws);
  k_gemm<<<(C_CLS + NT - 1) / NT, 512, 0, stream>>>(xnf, weight, bias, ws);
  k_label<<<BROWS, 64, 0, stream>>>(input, weight, label, bias, ws);
  k_final<<<1, 64, 0, stream>>>(ws, out);
}

// Round 8
// 160.963 us; speedup vs baseline: 1.7493x; 1.7493x over previous
//
#include <hip/hip_runtime.h>
#include <hip/hip_bf16.h>
#include <stdint.h>

// ---- problem constants ----
#define C_CLS  100000
#define DDIM   512
#define BROWS  512
#define NT     64          // classes per block
#define NSTEP  16          // K steps of 32
#define EPSN   1e-5f

typedef __attribute__((ext_vector_type(8))) short short8;
typedef __attribute__((ext_vector_type(4))) float f32x4;

// d_ws float layout:
//   [0    .. 4096)  : 256 gemm accumulation slots, stride 16 floats
//   [4096 .. 5120)  : 64 label accumulation slots, stride 16 floats
//   byte 32768 ...  : xnf — bf16 A in MFMA fragment layout (512 KB)

__device__ inline unsigned pk2(float a, float b) {
  __hip_bfloat162 h = __float22bfloat162_rn(make_float2(a, b));
  unsigned u; __builtin_memcpy(&u, &h, 4); return u;
}

// Normalize each input row -> bf16, fragment order:
// cell idx (16B) = (s*32 + r16)*64 + khalf*16 + row; s=k>>5, r16=b>>4,
// khalf=(k>>3)&3, row=b&15. Also zeroes the ws accumulation slots.
__global__ void __launch_bounds__(64) k_norm_input(const float* __restrict__ in,
                                                   uint4* __restrict__ xnf,
                                                   float* __restrict__ ws) {
  int b = blockIdx.x;
  int lane = threadIdx.x;              // lane covers k = lane*8 .. +7
  if (lane == 0) {                     // zero accumulation slots
    if (b < 256) ws[b * 16] = 0.f;
    else if (b < 320) ws[4096 + (b - 256) * 16] = 0.f;
  }
  const float4* row = (const float4*)(in + b * DDIM);
  float4 v0 = row[lane * 2];
  float4 v1 = row[lane * 2 + 1];
  float ss = v0.x*v0.x + v0.y*v0.y + v0.z*v0.z + v0.w*v0.w
           + v1.x*v1.x + v1.y*v1.y + v1.z*v1.z + v1.w*v1.w;
#pragma unroll
  for (int o = 32; o >= 1; o >>= 1) ss += __shfl_xor(ss, o, 64);
  float sc = 1.f / fmaxf(sqrtf(ss), EPSN);
  uint4 o4;
  o4.x = pk2(v0.x*sc, v0.y*sc);
  o4.y = pk2(v0.z*sc, v0.w*sc);
  o4.z = pk2(v1.x*sc, v1.y*sc);
  o4.w = pk2(v1.z*sc, v1.w*sc);
  int idx = ((lane >> 2) * 32 + (b >> 4)) * 64 + (lane & 3) * 16 + (b & 15);
  xnf[idx] = o4;
}

// Fused GEMM + loss. 512 threads (8 waves), wave owns 64 rows (m=4), NT=64.
// W path: global_load_lds DMA (f32, zero-reg, zero-VALU) -> 64KB LDS half-
// panel -> LDS->LDS cvt pass into bf16 frag-layout sW -> R5-proven consumer.
// Halves pipelined: DMA(h1) overlaps compute(h0). Block is W-stream-bound.
__global__ void __launch_bounds__(512, 2)
k_gemm(const uint4* __restrict__ xnf, const float* __restrict__ wt,
       const float* __restrict__ bias, float* __restrict__ ws) {
  __shared__ __align__(16) unsigned char sF[NT * 1024];      // f32 half-panel [64][256]
  __shared__ __align__(16) unsigned char sW[NSTEP * 4096];   // bf16 frag panel
  __shared__ float sNsq[NT];
  __shared__ float sRed[8];

  const int tid  = threadIdx.x;
  const int lane = tid & 63;
  const int wv   = tid >> 6;
  const int cbase = blockIdx.x * NT;

  // --- DMA one K-half of the W panel: 8 issues/wave, 1KB each (one row-half)
  auto dmaHalf = [&](int h) {
#pragma unroll
    for (int i = 0; i < 8; ++i) {
      int c = i * 8 + wv;                       // class row 0..63
      int cc = cbase + c;
      if (cc >= C_CLS) cc = C_CLS - 1;          // clamp; masked in epilogue
      const float* src = wt + (size_t)cc * DDIM + h * 256 + lane * 4;
      __builtin_amdgcn_global_load_lds(
          (const __attribute__((address_space(1))) unsigned int*)src,
          (__attribute__((address_space(3))) unsigned int*)(sF + c * 1024),
          16, 0, 0);
    }
  };

  // --- LDS->LDS cvt: f32 half-panel -> bf16 frag cells (+ norm^2) ---
  // lane l of pass p handles row c = p*8+wv, k = h*256 + l*4 .. +4:
  // step s = h*8 + (l>>3), khalf = (l&7)>>1, halfsel = l&1.
  auto cvtHalf = [&](int h) {
#pragma unroll
    for (int p = 0; p < 8; ++p) {
      int c = p * 8 + wv;
      float4 v = *(const float4*)(sF + c * 1024 + lane * 16);
      float sq = v.x*v.x + v.y*v.y + v.z*v.z + v.w*v.w;
#pragma unroll
      for (int o = 32; o >= 1; o >>= 1) sq += __shfl_xor(sq, o, 64);
      int s  = h * 8 + (lane >> 3);
      int kh = (lane & 7) >> 1;
      int cell = ((c >> 4) * 64 + kh * 16 + (c & 15)) * 16;
      int byte = (cell ^ (((kh ^ s) & 3) << 4)) + (lane & 1) * 8;
      uint2 d; d.x = pk2(v.x, v.y); d.y = pk2(v.z, v.w);
      *(uint2*)(sW + s * 4096 + byte) = d;
      if (lane == 0) { if (h) sNsq[c] += sq; else sNsq[c] = sq; }
    }
  };

  f32x4 acc[4][4];
#pragma unroll
  for (int m = 0; m < 4; m++)
#pragma unroll
    for (int n = 0; n < 4; n++) acc[m][n] = (f32x4)(0.f);

  const uint4* abase = xnf + wv * 256 + lane;   // + s*2048 + m*64

  // --- consumer: 8 steps of one half ---
  auto computeHalf = [&](int h) {
#pragma unroll 2
    for (int sl = 0; sl < 8; ++sl) {
      int s = h * 8 + sl;
      short8 af[4];
#pragma unroll
      for (int m = 0; m < 4; m++)
        af[m] = *(const short8*)(abase + s * 2048 + m * 64);
      const unsigned char* Wb = sW + s * 4096;
      const int rbyte = (lane * 16) ^ ((((lane >> 4) ^ s) & 3) << 4);
#pragma unroll
      for (int n = 0; n < 4; n++) {
        short8 wf = *(const short8*)(Wb + n * 1024 + rbyte);
#pragma unroll
        for (int m = 0; m < 4; m++)
          acc[m][n] = __builtin_amdgcn_mfma_f32_16x16x32_bf16(af[m], wf, acc[m][n], 0, 0, 0);
      }
    }
  };

  // --- schedule: DMA h0 | wait | cvt h0 | bar | DMA h1 + compute h0 |
  //               wait (drains h1) | cvt h1 | bar | compute h1 ---
  dmaHalf(0);
  __syncthreads();        // vmcnt(0)+barrier: h0 f32 landed for all waves
  cvtHalf(0);
  __syncthreads();        // sW h0 ready; sF reusable
  dmaHalf(1);             // in flight under compute h0
  computeHalf(0);
  __syncthreads();        // vmcnt(0)+barrier: h1 landed
  cvtHalf(1);
  __syncthreads();        // sW h1 + sNsq complete
  computeHalf(1);

  // ---- epilogue: loss over 64 acc elements / thread ----
  const float bv = bias[0];
  float lsum = 0.f;
#pragma unroll
  for (int n = 0; n < 4; n++) {
    int cl = n * 16 + (lane & 15);
    float s64 = 64.f / fmaxf(sqrtf(sNsq[cl]), EPSN);   // fold S and 1/||w||
    bool valid = (cbase + cl) < C_CLS;
#pragma unroll
    for (int m = 0; m < 4; m++) {
#pragma unroll
      for (int i = 0; i < 4; i++) {
        // x = 64*cos - bias <= ~51: upper clamp provably inactive; lower
        // clip irrelevant (exp underflow). log1p(z) ~= z - z^2/2, z<=1/32.
        float x = fmaf(acc[m][n][i], s64, -bv);
        float z = __expf(x);
        float l = fmaf(-0.5f * z, z, z);
        if (z > 0.03125f) l = __logf(1.f + z);   // rare (~1e-4)
        lsum += valid ? l : 0.f;
      }
    }
  }
#pragma unroll
  for (int o = 32; o >= 1; o >>= 1) lsum += __shfl_xor(lsum, o, 64);
  if (lane == 0) sRed[wv] = lsum;
  __syncthreads();
  if (tid == 0) {
    float t = 0.f;
#pragma unroll
    for (int i = 0; i < 8; i++) t += sRed[i];
    atomicAdd(&ws[(blockIdx.x & 255) * 16], t);
  }
}

// Label correction: replace n_loss(b, label_b) by p_loss(b, label_b), full f32.
__global__ void __launch_bounds__(64) k_label(const float* __restrict__ in,
                                              const float* __restrict__ wt,
                                              const int* __restrict__ label,
                                              const float* __restrict__ bias,
                                              float* __restrict__ ws) {
  int b = blockIdx.x;
  int lane = threadIdx.x;
  int c = label[b];
  const float4* xr = (const float4*)(in + b * DDIM);
  const float4* wr = (const float4*)(wt + (size_t)c * DDIM);
  float dt = 0.f, sx = 0.f, sw = 0.f;
#pragma unroll
  for (int i = 0; i < 2; i++) {
    float4 x = xr[lane * 2 + i];
    float4 w = wr[lane * 2 + i];
    dt += x.x*w.x + x.y*w.y + x.z*w.z + x.w*w.w;
    sx += x.x*x.x + x.y*x.y + x.z*x.z + x.w*x.w;
    sw += w.x*w.x + w.y*w.y + w.z*w.z + w.w*w.w;
  }
#pragma unroll
  for (int o = 32; o >= 1; o >>= 1) {
    dt += __shfl_xor(dt, o, 64);
    sx += __shfl_xor(sx, o, 64);
    sw += __shfl_xor(sw, o, 64);
  }
  if (lane == 0) {
    float bv = bias[0];
    float cosv = dt / (fmaxf(sqrtf(sx), EPSN) * fmaxf(sqrtf(sw), EPSN));
    float cp = 64.f * (cosv - 0.4f) - bv;
    cp = fminf(fmaxf(cp, -64.f), 64.f);
    float pl = log1pf(expf(-cp));
    float cn = 64.f * cosv - bv;
    cn = fminf(fmaxf(cn, -64.f), 64.f);
    float nl = log1pf(expf(cn));
    atomicAdd(&ws[4096 + (b & 63) * 16], pl - nl);
  }
}

// Merge the 256 gemm slots + 64 label slots, scale by 1/B.
__global__ void __launch_bounds__(64) k_final(const float* __restrict__ ws,
                                              float* __restrict__ out) {
  int lane = threadIdx.x;
  float s = ws[lane * 16] + ws[(lane + 64) * 16]
          + ws[(lane + 128) * 16] + ws[(lane + 192) * 16]
          + ws[4096 + lane * 16];
#pragma unroll
  for (int o = 32; o >= 1; o >>= 1) s += __shfl_xor(s, o, 64);
  if (lane == 0) out[0] = s * (1.f / 512.f);
}

extern "C" void kernel_launch(void* const* d_in, const int* in_sizes, int n_in,
                              void* d_out, int out_size, void* d_ws, size_t ws_size,
                              hipStream_t stream) {
  const float* input  = (const float*)d_in[0];
  const int*   label  = (const int*)d_in[1];
  const float* weight = (const float*)d_in[2];
  const float* bias   = (const float*)d_in[3];
  float* out = (float*)d_out;
  float* ws  = (float*)d_ws;
  uint4* xnf = (uint4*)((char*)d_ws + 32768);

  k_norm_input<<<BROWS, 64, 0, stream>>>(input, xnf, ws);
  k_gemm<<<(C_CLS + NT - 1) / NT, 512, 0, stream>>>(xnf, weight, bias, ws);
  k_label<<<BROWS, 64, 0, stream>>>(input, weight, label, bias, ws);
  k_final<<<1, 64, 0, stream>>>(ws, out);
}

// Round 9
// 159.094 us; speedup vs baseline: 1.7698x; 1.0117x over previous
//
#include <hip/hip_runtime.h>
#include <hip/hip_bf16.h>
#include <stdint.h>

// ---- problem constants ----
#define C_CLS  100000
#define DDIM   512
#define BROWS  512
#define NT     64          // classes per block
#define EPSN   1e-5f

typedef __attribute__((ext_vector_type(8))) short short8;
typedef __attribute__((ext_vector_type(4))) float f32x4;

// d_ws float layout:
//   [0    .. 4096)  : 256 gemm accumulation slots, stride 16 floats
//   [4096 .. 5120)  : 64 label accumulation slots, stride 16 floats
//   byte 32768 ...  : xnf — bf16 A in MFMA fragment layout (512 KB)

__device__ inline unsigned pk2(float a, float b) {
  __hip_bfloat162 h = __float22bfloat162_rn(make_float2(a, b));
  unsigned u; __builtin_memcpy(&u, &h, 4); return u;
}

// Normalize each input row -> bf16, fragment order:
// cell idx (16B) = (s*32 + r16)*64 + khalf*16 + row; s=k>>5, r16=b>>4,
// khalf=(k>>3)&3, row=b&15. Also zeroes the ws accumulation slots.
__global__ void __launch_bounds__(64) k_norm_input(const float* __restrict__ in,
                                                   uint4* __restrict__ xnf,
                                                   float* __restrict__ ws) {
  int b = blockIdx.x;
  int lane = threadIdx.x;              // lane covers k = lane*8 .. +7
  if (lane == 0) {                     // zero accumulation slots
    if (b < 256) ws[b * 16] = 0.f;
    else if (b < 320) ws[4096 + (b - 256) * 16] = 0.f;
  }
  const float4* row = (const float4*)(in + b * DDIM);
  float4 v0 = row[lane * 2];
  float4 v1 = row[lane * 2 + 1];
  float ss = v0.x*v0.x + v0.y*v0.y + v0.z*v0.z + v0.w*v0.w
           + v1.x*v1.x + v1.y*v1.y + v1.z*v1.z + v1.w*v1.w;
#pragma unroll
  for (int o = 32; o >= 1; o >>= 1) ss += __shfl_xor(ss, o, 64);
  float sc = 1.f / fmaxf(sqrtf(ss), EPSN);
  uint4 o4;
  o4.x = pk2(v0.x*sc, v0.y*sc);
  o4.y = pk2(v0.z*sc, v0.w*sc);
  o4.z = pk2(v1.x*sc, v1.y*sc);
  o4.w = pk2(v1.z*sc, v1.w*sc);
  int idx = ((lane >> 2) * 32 + (b >> 4)) * 64 + (lane & 3) * 16 + (b & 15);
  xnf[idx] = o4;
}

// Fused GEMM + loss. 512 threads (8 waves), wave owns 64 rows (m=4), NT=64.
// W path: global_load_lds DMA of f32 eighth-panels (64 cls x 64 k = 16 KB)
// into a 2-buffer pipeline; consumer ds_reads f32, converts to bf16 in regs,
// MFMAs. No separate cvt pass, no sW, 1 barrier per 2 K-steps. Source
// addresses pre-swizzled (granule ^ row) so strided reads are conflict-free.
__global__ void __launch_bounds__(512, 4)
k_gemm(const uint4* __restrict__ xnf, const float* __restrict__ wt,
       const float* __restrict__ bias, float* __restrict__ ws) {
  __shared__ __align__(16) unsigned char sF[2][16384];   // [row 0..63][256 B]
  __shared__ float sRed[8];

  const int tid  = threadIdx.x;
  const int lane = tid & 63;
  const int wv   = tid >> 6;
  const int cbase = blockIdx.x * NT;
  const int rloc = lane >> 4;          // 0..3
  const int g16  = lane & 15;          // granule / class-in-frag

  // DMA one eighth (k-chunk of 64 f32 per class row): 2 instrs/wave, 1 KB each.
  // Instr i covers rows wv*8 + i*4 .. +4; lane l -> row +(l>>4), granule
  // (l&15), source granule XOR-swizzled by row for conflict-free reads.
  auto dma = [&](int e, int buf) {
#pragma unroll
    for (int i = 0; i < 2; ++i) {
      int row = wv * 8 + i * 4 + rloc;
      int cc = cbase + row;
      if (cc >= C_CLS) cc = C_CLS - 1;           // clamp; masked in epilogue
      const float* src = wt + (size_t)cc * DDIM + e * 64 + ((g16 ^ (row & 15)) << 2);
      __builtin_amdgcn_global_load_lds(
          (const __attribute__((address_space(1))) unsigned int*)src,
          (__attribute__((address_space(3))) unsigned int*)(&sF[buf][(wv * 2 + i) * 1024]),
          16, 0, 0);
    }
  };

  float wsq[4] = {0.f, 0.f, 0.f, 0.f};
  f32x4 acc[4][4];
#pragma unroll
  for (int m = 0; m < 4; m++)
#pragma unroll
    for (int n = 0; n < 4; n++) acc[m][n] = (f32x4)(0.f);

  // one K-step (K=32): 4 A-frags from L2 (xnf frag layout), 4 B-frags read
  // as f32 from sF (+swizzle), cvt to bf16 in regs (+ norm^2), 16 MFMA.
  auto step = [&](int s, int buf) {
    const int sl = s & 1;
    short8 af[4];
    const uint4* ap = xnf + s * 2048 + wv * 256 + lane;
#pragma unroll
    for (int m = 0; m < 4; m++) af[m] = *(const short8*)(ap + m * 64);
    short8 wf[4];
    const unsigned char* fb = sF[buf];
    const int gb = sl * 8 + rloc * 2;            // k-granule base (16B units)
#pragma unroll
    for (int n = 0; n < 4; n++) {
      const unsigned char* rp = fb + (n * 16 + g16) * 256;
      float4 b0 = *(const float4*)(rp + ((gb ^ g16) << 4));
      float4 b1 = *(const float4*)(rp + (((gb + 1) ^ g16) << 4));
      wsq[n] += b0.x*b0.x + b0.y*b0.y + b0.z*b0.z + b0.w*b0.w
              + b1.x*b1.x + b1.y*b1.y + b1.z*b1.z + b1.w*b1.w;
      uint4 u;
      u.x = pk2(b0.x, b0.y); u.y = pk2(b0.z, b0.w);
      u.z = pk2(b1.x, b1.y); u.w = pk2(b1.z, b1.w);
      __builtin_memcpy(&wf[n], &u, 16);
    }
#pragma unroll
    for (int n = 0; n < 4; n++)
#pragma unroll
      for (int m = 0; m < 4; m++)
        acc[m][n] = __builtin_amdgcn_mfma_f32_16x16x32_bf16(af[m], wf[n], acc[m][n], 0, 0, 0);
  };

  // pipeline: DMA(e+1) in flight while computing eighth e (2 K-steps);
  // __syncthreads' vmcnt(0) drain == wait for the next eighth's data.
  dma(0, 0);
  __syncthreads();
#pragma unroll 1
  for (int g = 0; g < 8; ++g) {
    if (g < 7) dma(g + 1, (g + 1) & 1);
    step(2 * g,     g & 1);
    step(2 * g + 1, g & 1);
    __syncthreads();
  }

  // ---- epilogue: finish norms (2 shfl), loss over 64 elems/thread ----
  const float bv = bias[0];
  float lsum = 0.f;
#pragma unroll
  for (int n = 0; n < 4; n++) {
    float t = wsq[n];
    t += __shfl_xor(t, 16, 64);
    t += __shfl_xor(t, 32, 64);                  // 4 k-groups summed
    float s64 = 64.f / fmaxf(sqrtf(t), EPSN);    // fold S and 1/||w||
    bool valid = (cbase + n * 16 + g16) < C_CLS;
#pragma unroll
    for (int m = 0; m < 4; m++) {
#pragma unroll
      for (int i = 0; i < 4; i++) {
        // x = 64*cos - bias <= ~51: upper clamp provably inactive; lower
        // clip irrelevant (exp underflow). log1p(z) ~= z - z^2/2, z<=1/32.
        float x = fmaf(acc[m][n][i], s64, -bv);
        float z = __expf(x);
        float l = fmaf(-0.5f * z, z, z);
        if (z > 0.03125f) l = __logf(1.f + z);   // rare (~1e-4)
        lsum += valid ? l : 0.f;
      }
    }
  }
#pragma unroll
  for (int o = 32; o >= 1; o >>= 1) lsum += __shfl_xor(lsum, o, 64);
  if (lane == 0) sRed[wv] = lsum;
  __syncthreads();
  if (tid == 0) {
    float t = 0.f;
#pragma unroll
    for (int i = 0; i < 8; i++) t += sRed[i];
    atomicAdd(&ws[(blockIdx.x & 255) * 16], t);
  }
}

// Label correction: replace n_loss(b, label_b) by p_loss(b, label_b), full f32.
__global__ void __launch_bounds__(64) k_label(const float* __restrict__ in,
                                              const float* __restrict__ wt,
                                              const int* __restrict__ label,
                                              const float* __restrict__ bias,
                                              float* __restrict__ ws) {
  int b = blockIdx.x;
  int lane = threadIdx.x;
  int c = label[b];
  const float4* xr = (const float4*)(in + b * DDIM);
  const float4* wr = (const float4*)(wt + (size_t)c * DDIM);
  float dt = 0.f, sx = 0.f, sw = 0.f;
#pragma unroll
  for (int i = 0; i < 2; i++) {
    float4 x = xr[lane * 2 + i];
    float4 w = wr[lane * 2 + i];
    dt += x.x*w.x + x.y*w.y + x.z*w.z + x.w*w.w;
    sx += x.x*x.x + x.y*x.y + x.z*x.z + x.w*x.w;
    sw += w.x*w.x + w.y*w.y + w.z*w.z + w.w*w.w;
  }
#pragma unroll
  for (int o = 32; o >= 1; o >>= 1) {
    dt += __shfl_xor(dt, o, 64);
    sx += __shfl_xor(sx, o, 64);
    sw += __shfl_xor(sw, o, 64);
  }
  if (lane == 0) {
    float bv = bias[0];
    float cosv = dt / (fmaxf(sqrtf(sx), EPSN) * fmaxf(sqrtf(sw), EPSN));
    float cp = 64.f * (cosv - 0.4f) - bv;
    cp = fminf(fmaxf(cp, -64.f), 64.f);
    float pl = log1pf(expf(-cp));
    float cn = 64.f * cosv - bv;
    cn = fminf(fmaxf(cn, -64.f), 64.f);
    float nl = log1pf(expf(cn));
    atomicAdd(&ws[4096 + (b & 63) * 16], pl - nl);
  }
}

// Merge the 256 gemm slots + 64 label slots, scale by 1/B.
__global__ void __launch_bounds__(64) k_final(const float* __restrict__ ws,
                                              float* __restrict__ out) {
  int lane = threadIdx.x;
  float s = ws[lane * 16] + ws[(lane + 64) * 16]
          + ws[(lane + 128) * 16] + ws[(lane + 192) * 16]
          + ws[4096 + lane * 16];
#pragma unroll
  for (int o = 32; o >= 1; o >>= 1) s += __shfl_xor(s, o, 64);
  if (lane == 0) out[0] = s * (1.f / 512.f);
}

extern "C" void kernel_launch(void* const* d_in, const int* in_sizes, int n_in,
                              void* d_out, int out_size, void* d_ws, size_t ws_size,
                              hipStream_t stream) {
  const float* input  = (const float*)d_in[0];
  const int*   label  = (const int*)d_in[1];
  const float* weight = (const float*)d_in[2];
  const float* bias   = (const float*)d_in[3];
  float* out = (float*)d_out;
  float* ws  = (float*)d_ws;
  uint4* xnf = (uint4*)((char*)d_ws + 32768);

  k_norm_input<<<BROWS, 64, 0, stream>>>(input, xnf, ws);
  k_gemm<<<(C_CLS + NT - 1) / NT, 512, 0, stream>>>(xnf, weight, bias, ws);
  k_label<<<BROWS, 64, 0, stream>>>(input, weight, label, bias, ws);
  k_final<<<1, 64, 0, stream>>>(ws, out);
}